// Round 9
// baseline (707.445 us; speedup 1.0000x reference)
//
#include <hip/hip_runtime.h>
#include <hip/hip_bf16.h>
#include <hip/hip_fp16.h>

#define NDIM 100
#define HDIM 16
#define CDIM 20

#define BSH2   10                 // 1024 nodes per bucket
#define BMASK2 ((1 << BSH2) - 1)
#define NB2MAX 768                // supports N <= 786432
#define CH2    16384              // edges per scatter_sort block
#define CHSH   17                 // src chunk = src >> 17 (128K nodes = 4MB fp16 table)

// fp16 pack/unpack helpers (tables stored fp16, accumulation fp32)
__device__ inline float2 h2f2(unsigned u) {
    __half2 h = *reinterpret_cast<__half2*>(&u);
    return __half22float2(h);
}
__device__ inline unsigned f2h2(float a, float b) {
    __half2 h = __floats2half2_rn(a, b);
    return *reinterpret_cast<unsigned*>(&h);
}

// ---------------- pass A: bucket histogram -> bcnt[b] ----------------

__global__ __launch_bounds__(256) void histA(const int* __restrict__ dst,
                                             int* __restrict__ bcnt,
                                             int E, int NB2) {
    __shared__ int lh[NB2MAX];
    for (int t = threadIdx.x; t < NB2MAX; t += 256) lh[t] = 0;
    __syncthreads();

    int base = blockIdx.x * 8192;
    int endv = min(base + 8192, E);
    for (int e = base + threadIdx.x; e < endv; e += 256)
        atomicAdd(&lh[dst[e] >> BSH2], 1);
    __syncthreads();

    for (int t = threadIdx.x; t < NB2; t += 256) {
        int v = lh[t];
        if (v) atomicAdd(&bcnt[t], v);
    }
}

// ---- exclusive scan of bcnt in place (nb <= 2048), 1 block; also seeds gcur ----

__global__ __launch_bounds__(256) void scan_k2(int* __restrict__ bsum,
                                               int* __restrict__ gcur, int nb) {
    __shared__ int part[256];
    int t = threadIdx.x;
    int base = t * 8;
    int loc[8];
    int s = 0;
#pragma unroll
    for (int k = 0; k < 8; ++k) {
        int idx = base + k;
        loc[k] = (idx < nb) ? bsum[idx] : 0;
        s += loc[k];
    }
    part[t] = s;
    __syncthreads();
    for (int off = 1; off < 256; off <<= 1) {
        int add = (t >= off) ? part[t - off] : 0;
        __syncthreads();
        part[t] += add;
        __syncthreads();
    }
    int run = (t > 0) ? part[t - 1] : 0;
#pragma unroll
    for (int k = 0; k < 8; ++k) {
        int idx = base + k;
        if (idx < nb) { bsum[idx] = run; gcur[idx] = run; }
        run += loc[k];
    }
}

// ---------------- pass B: block-local counting sort in LDS + full-line copy-out ----

__global__ __launch_bounds__(1024) void scatter_sort(const int* __restrict__ src,
                                                     const int* __restrict__ dst,
                                                     int* __restrict__ gcur,
                                                     unsigned* __restrict__ tmp,
                                                     int E, int NB2) {
    __shared__ unsigned lbuf[CH2];   // 64 KB
    __shared__ int lcnt[1024];       // counts -> cursors
    __shared__ int lst[1024];        // local exclusive starts
    __shared__ int gb[1024];         // global run bases
    const int t = threadIdx.x;

    lcnt[t] = 0;
    __syncthreads();

    int base = blockIdx.x * CH2;
    int endv = min(base + CH2, E);
    for (int e = base + t; e < endv; e += 1024)
        atomicAdd(&lcnt[dst[e] >> BSH2], 1);
    __syncthreads();

    int c = lcnt[t];
    lst[t] = c;
    __syncthreads();
    for (int off = 1; off < 1024; off <<= 1) {
        int add = (t >= off) ? lst[t - off] : 0;
        __syncthreads();
        lst[t] += add;
        __syncthreads();
    }
    int ex = lst[t] - c;   // exclusive prefix

    int gbase = 0;
    if (t < NB2 && c > 0) gbase = atomicAdd(&gcur[t], c);
    gb[t]   = gbase;
    lst[t]  = ex;
    lcnt[t] = ex;
    __syncthreads();

    for (int e = base + t; e < endv; e += 1024) {
        int d = dst[e];
        int b = d >> BSH2;
        int pos = atomicAdd(&lcnt[b], 1);
        lbuf[pos] = ((unsigned)src[e] << BSH2) | (unsigned)(d & BMASK2);
    }
    __syncthreads();

    int grp = t >> 4, lane = t & 15;
    for (int b = grp; b < NB2; b += 64) {
        int s0 = lst[b], g0 = gb[b];
        int len = lcnt[b] - s0;
        for (int k = lane; k < len; k += 16)
            tmp[(size_t)g0 + k] = lbuf[s0 + k];
    }
}

// ---------------- pass C: (node, src-chunk) counting sort, direct scatter ----------------
// One block per bucket; esrc window [lo,hi) is block-exclusive -> L2 merges the
// scattered 4B writes into full lines. Emits segc=(end,deg,chunk-lens) + dinv.

__global__ __launch_bounds__(1024) void binC(const unsigned* __restrict__ tmp,
                                             const int* __restrict__ B0,
                                             int4* __restrict__ segc,
                                             float* __restrict__ dinv,
                                             int* __restrict__ esrc,
                                             int N, int E, int NB2) {
    __shared__ int lh[4096];    // (node,chunk) counts -> global cursors
    __shared__ int part[1024];
    int b = blockIdx.x, t = threadIdx.x;

    for (int i = t; i < 4096; i += 1024) lh[i] = 0;
    __syncthreads();

    int lo = B0[b];
    int hi = (b + 1 < NB2) ? B0[b + 1] : E;

    for (int i = lo + t; i < hi; i += 1024) {
        unsigned v = tmp[i];
        unsigned ch = min(v >> (BSH2 + CHSH), 3u);
        atomicAdd(&lh[((v & BMASK2) << 2) | ch], 1);
    }
    __syncthreads();

    int c0 = lh[4 * t], c1 = lh[4 * t + 1], c2 = lh[4 * t + 2], c3 = lh[4 * t + 3];
    int cnt = c0 + c1 + c2 + c3;
    part[t] = cnt;
    __syncthreads();
    for (int off = 1; off < 1024; off <<= 1) {
        int add = (t >= off) ? part[t - off] : 0;
        __syncthreads();
        part[t] += add;
        __syncthreads();
    }
    int endl = part[t];        // inclusive
    int st   = endl - cnt;     // node-local segment start

    lh[4 * t]     = lo + st;
    lh[4 * t + 1] = lo + st + c0;
    lh[4 * t + 2] = lo + st + c0 + c1;
    lh[4 * t + 3] = lo + st + c0 + c1 + c2;

    int node = (b << BSH2) + t;
    if (node < N) {
        segc[node] = make_int4(lo + endl, cnt, (c0 << 16) | c1, (c2 << 16) | c3);
        dinv[node] = rsqrtf((float)(cnt + 1));   // +1 = self-loop
    }
    __syncthreads();

    // direct scatter into the block-exclusive esrc window
    for (int i = lo + t; i < hi; i += 1024) {
        unsigned v = tmp[i];
        unsigned srcv = v >> BSH2;
        unsigned ch = min(srcv >> CHSH, 3u);
        int pos = atomicAdd(&lh[((v & BMASK2) << 2) | ch], 1);
        esrc[pos] = (int)srcv;
    }
}

// ---------------- xw1h = fp16( dinv[n] * (x @ W1) )  ([N,100] @ [100,16]) ----------------

__global__ __launch_bounds__(256) void xw1_kernel(const float* __restrict__ x,
                                                  const float* __restrict__ W1,
                                                  const float* __restrict__ dinv,
                                                  __half* __restrict__ xw1h, int N) {
    __shared__ float Ws[NDIM * HDIM];  // [k][j]
    for (int t = threadIdx.x; t < NDIM * HDIM; t += 256) Ws[t] = W1[t];
    __syncthreads();

    const int ln = threadIdx.x >> 2;
    const int q  = threadIdx.x & 3;
    const int node = blockIdx.x * 64 + ln;
    if (node >= N) return;

    const float4* xr  = reinterpret_cast<const float4*>(x + (size_t)node * NDIM);
    const float4* Ws4 = reinterpret_cast<const float4*>(Ws);

    float4 acc = make_float4(0.f, 0.f, 0.f, 0.f);
#pragma unroll
    for (int kk = 0; kk < NDIM / 4; ++kk) {
        float4 xv = xr[kk];
        float xs[4] = {xv.x, xv.y, xv.z, xv.w};
#pragma unroll
        for (int c = 0; c < 4; ++c) {
            float4 w = Ws4[(kk * 4 + c) * 4 + q];
            acc.x += xs[c] * w.x;
            acc.y += xs[c] * w.y;
            acc.z += xs[c] * w.z;
            acc.w += xs[c] * w.w;
        }
    }
    float dn = dinv[node];
    uint2 o;
    o.x = f2h2(dn * acc.x, dn * acc.y);
    o.y = f2h2(dn * acc.z, dn * acc.w);
    reinterpret_cast<uint2*>(xw1h)[(size_t)node * 4 + q] = o;
}

// ---------------- layer-1 gather (4 src-chunk phases): hsh = fp16(...) ----------------
// 4 lanes per node, 64 nodes per 256-thread block; __syncthreads between chunk
// phases keeps all waves of the block inside one 4MB table slice at a time.

__global__ __launch_bounds__(256) void gather1(const int* __restrict__ esrc,
                                               const int4* __restrict__ segc,
                                               const float* __restrict__ dinv,
                                               const __half* __restrict__ xw1h,
                                               const float* __restrict__ b1,
                                               __half* __restrict__ hsh, int N) {
    int g  = threadIdx.x >> 2;
    int f4 = threadIdx.x & 3;
    int n  = blockIdx.x * 64 + g;
    bool active = (n < N);

    const uint2* T = reinterpret_cast<const uint2*>(xw1h);
    int4 sc = make_int4(0, 0, 0, 0);
    float dn = 0.f;
    float4 a0 = make_float4(0.f, 0.f, 0.f, 0.f);
    float4 a1 = make_float4(0.f, 0.f, 0.f, 0.f);
    if (active) {
        sc = segc[n];
        dn = dinv[n];
        uint2 sv = T[(size_t)n * 4 + f4];
        float2 s01 = h2f2(sv.x), s23 = h2f2(sv.y);
        a0 = make_float4(s01.x, s01.y, s23.x, s23.y);  // self term
    }
    int lens[4] = {sc.z >> 16, sc.z & 0xffff, sc.w >> 16, sc.w & 0xffff};
    int j = sc.x - sc.y;  // start

    for (int c = 0; c < 4; ++c) {
        int e2 = j + lens[c];
        for (; j + 3 < e2; j += 4) {
            int i0 = esrc[j + 0], i1 = esrc[j + 1];
            int i2 = esrc[j + 2], i3 = esrc[j + 3];
            uint2 v0 = T[(size_t)i0 * 4 + f4];
            uint2 v1 = T[(size_t)i1 * 4 + f4];
            uint2 v2 = T[(size_t)i2 * 4 + f4];
            uint2 v3 = T[(size_t)i3 * 4 + f4];
            float2 p, q;
            p = h2f2(v0.x); q = h2f2(v0.y);
            a0.x += p.x; a0.y += p.y; a0.z += q.x; a0.w += q.y;
            p = h2f2(v1.x); q = h2f2(v1.y);
            a1.x += p.x; a1.y += p.y; a1.z += q.x; a1.w += q.y;
            p = h2f2(v2.x); q = h2f2(v2.y);
            a0.x += p.x; a0.y += p.y; a0.z += q.x; a0.w += q.y;
            p = h2f2(v3.x); q = h2f2(v3.y);
            a1.x += p.x; a1.y += p.y; a1.z += q.x; a1.w += q.y;
        }
        for (; j < e2; ++j) {
            int s = esrc[j];
            uint2 v = T[(size_t)s * 4 + f4];
            float2 p = h2f2(v.x), q = h2f2(v.y);
            a0.x += p.x; a0.y += p.y; a0.z += q.x; a0.w += q.y;
        }
        if (c < 3) __syncthreads();
    }
    if (active) {
        float4 acc = make_float4(a0.x + a1.x, a0.y + a1.y, a0.z + a1.z, a0.w + a1.w);
        float4 bv = reinterpret_cast<const float4*>(b1)[f4];
        float hx = dn * fmaxf(dn * acc.x + bv.x, 0.f);
        float hy = dn * fmaxf(dn * acc.y + bv.y, 0.f);
        float hz = dn * fmaxf(dn * acc.z + bv.z, 0.f);
        float hw = dn * fmaxf(dn * acc.w + bv.w, 0.f);
        uint2 o;
        o.x = f2h2(hx, hy);
        o.y = f2h2(hz, hw);
        reinterpret_cast<uint2*>(hsh)[(size_t)n * 4 + f4] = o;
    }
}

// ---------------- layer-2 gather (4 src-chunk phases): agg2 fp32 ----------------

__global__ __launch_bounds__(256) void gather2(const int* __restrict__ esrc,
                                               const int4* __restrict__ segc,
                                               const float* __restrict__ dinv,
                                               const __half* __restrict__ hsh,
                                               float* __restrict__ agg2, int N) {
    int g  = threadIdx.x >> 2;
    int f4 = threadIdx.x & 3;
    int n  = blockIdx.x * 64 + g;
    bool active = (n < N);

    const uint2* T = reinterpret_cast<const uint2*>(hsh);
    int4 sc = make_int4(0, 0, 0, 0);
    float dn = 0.f;
    float4 a0 = make_float4(0.f, 0.f, 0.f, 0.f);
    float4 a1 = make_float4(0.f, 0.f, 0.f, 0.f);
    if (active) {
        sc = segc[n];
        dn = dinv[n];
        uint2 sv = T[(size_t)n * 4 + f4];
        float2 s01 = h2f2(sv.x), s23 = h2f2(sv.y);
        a0 = make_float4(s01.x, s01.y, s23.x, s23.y);  // self term
    }
    int lens[4] = {sc.z >> 16, sc.z & 0xffff, sc.w >> 16, sc.w & 0xffff};
    int j = sc.x - sc.y;  // start

    for (int c = 0; c < 4; ++c) {
        int e2 = j + lens[c];
        for (; j + 3 < e2; j += 4) {
            int i0 = esrc[j + 0], i1 = esrc[j + 1];
            int i2 = esrc[j + 2], i3 = esrc[j + 3];
            uint2 v0 = T[(size_t)i0 * 4 + f4];
            uint2 v1 = T[(size_t)i1 * 4 + f4];
            uint2 v2 = T[(size_t)i2 * 4 + f4];
            uint2 v3 = T[(size_t)i3 * 4 + f4];
            float2 p, q;
            p = h2f2(v0.x); q = h2f2(v0.y);
            a0.x += p.x; a0.y += p.y; a0.z += q.x; a0.w += q.y;
            p = h2f2(v1.x); q = h2f2(v1.y);
            a1.x += p.x; a1.y += p.y; a1.z += q.x; a1.w += q.y;
            p = h2f2(v2.x); q = h2f2(v2.y);
            a0.x += p.x; a0.y += p.y; a0.z += q.x; a0.w += q.y;
            p = h2f2(v3.x); q = h2f2(v3.y);
            a1.x += p.x; a1.y += p.y; a1.z += q.x; a1.w += q.y;
        }
        for (; j < e2; ++j) {
            int s = esrc[j];
            uint2 v = T[(size_t)s * 4 + f4];
            float2 p = h2f2(v.x), q = h2f2(v.y);
            a0.x += p.x; a0.y += p.y; a0.z += q.x; a0.w += q.y;
        }
        if (c < 3) __syncthreads();
    }
    if (active) {
        float4 o;
        o.x = dn * (a0.x + a1.x);
        o.y = dn * (a0.y + a1.y);
        o.z = dn * (a0.z + a1.z);
        o.w = dn * (a0.w + a1.w);
        reinterpret_cast<float4*>(agg2)[(size_t)n * 4 + f4] = o;
    }
}

// ---------------- final: out = log_softmax(agg2 @ W2 + b2) ----------------

__global__ __launch_bounds__(256) void final_kernel(const float* __restrict__ agg2,
                                                    const float* __restrict__ W2,
                                                    const float* __restrict__ b2,
                                                    float* __restrict__ out, int N) {
    __shared__ float W2t[CDIM * HDIM];  // [j][k]
    __shared__ float b2s[CDIM];
    for (int t = threadIdx.x; t < CDIM * HDIM; t += 256) {
        int j = t / HDIM, k = t % HDIM;
        W2t[t] = W2[k * CDIM + j];
    }
    for (int t = threadIdx.x; t < CDIM; t += 256) b2s[t] = b2[t];
    __syncthreads();

    int n = blockIdx.x * 256 + threadIdx.x;
    if (n >= N) return;

    float a[HDIM];
    const float4* a4 = reinterpret_cast<const float4*>(agg2 + (size_t)n * HDIM);
#pragma unroll
    for (int c = 0; c < HDIM / 4; ++c) {
        float4 v = a4[c];
        a[4 * c + 0] = v.x; a[4 * c + 1] = v.y;
        a[4 * c + 2] = v.z; a[4 * c + 3] = v.w;
    }
    float o[CDIM];
#pragma unroll
    for (int j = 0; j < CDIM; ++j) {
        const float4* w4 = reinterpret_cast<const float4*>(W2t + j * HDIM);
        float s = b2s[j];
#pragma unroll
        for (int c = 0; c < HDIM / 4; ++c) {
            float4 w = w4[c];
            s += a[4 * c + 0] * w.x + a[4 * c + 1] * w.y +
                 a[4 * c + 2] * w.z + a[4 * c + 3] * w.w;
        }
        o[j] = s;
    }
    float m = o[0];
#pragma unroll
    for (int j = 1; j < CDIM; ++j) m = fmaxf(m, o[j]);
    float s = 0.f;
#pragma unroll
    for (int j = 0; j < CDIM; ++j) s += __expf(o[j] - m);
    float l = __logf(s);
    float4* out4 = reinterpret_cast<float4*>(out + (size_t)n * CDIM);
#pragma unroll
    for (int c = 0; c < CDIM / 4; ++c)
        out4[c] = make_float4(o[4 * c + 0] - m - l, o[4 * c + 1] - m - l,
                              o[4 * c + 2] - m - l, o[4 * c + 3] - m - l);
}

// ---------------- launch ----------------

extern "C" void kernel_launch(void* const* d_in, const int* in_sizes, int n_in,
                              void* d_out, int out_size, void* d_ws, size_t ws_size,
                              hipStream_t stream) {
    const float* x  = (const float*)d_in[0];
    const int* edge = (const int*)d_in[1];   // [2, E] int32
    const float* W1 = (const float*)d_in[2];
    const float* b1 = (const float*)d_in[3];
    const float* W2 = (const float*)d_in[4];
    const float* b2 = (const float*)d_in[5];
    float* out = (float*)d_out;

    const int N = in_sizes[0] / NDIM;   // 500000
    const int E = in_sizes[1] / 2;      // 8000000
    const int* src = edge;
    const int* dst = edge + E;

    const int tb = 256;
    const int nbN = (N + tb - 1) / tb;
    const int NB2 = (N + BMASK2) >> BSH2;       // 489 coarse buckets

    char* ws = (char*)d_ws;
    size_t off = 0;
    int4*     segc   = (int4*)(ws + off);   off += (size_t)N * 16;
    float*    dinv   = (float*)(ws + off);  off += (size_t)N * 4;
    __half*   xw1h   = (__half*)(ws + off); off += (size_t)N * HDIM * 2;
    __half*   hsh    = (__half*)(ws + off); off += (size_t)N * HDIM * 2;
    float*    agg2   = (float*)(ws + off);  off += (size_t)N * HDIM * 4;
    int*      esrc   = (int*)(ws + off);    off += (size_t)E * 4;
    int*      bcnt   = (int*)(ws + off);    off += (size_t)NB2MAX * 4;
    int*      gcur   = (int*)(ws + off);    off += (size_t)NB2MAX * 4;

    // tmp (bucket-major packed edges, E*4 = 32MB) aliases agg2 (N*HDIM*4 = 32MB);
    // agg2 is only written by gather2, long after binC has consumed tmp.
    unsigned* tmp = (unsigned*)agg2;

    // ---- CSR build ----
    hipMemsetAsync(bcnt, 0, (size_t)NB2 * 4, stream);
    histA<<<(E + 8191) / 8192, tb, 0, stream>>>(dst, bcnt, E, NB2);
    scan_k2<<<1, tb, 0, stream>>>(bcnt, gcur, NB2);   // bcnt -> B0, seeds gcur
    scatter_sort<<<(E + CH2 - 1) / CH2, 1024, 0, stream>>>(src, dst, gcur, tmp, E, NB2);
    binC<<<NB2, 1024, 0, stream>>>(tmp, bcnt, segc, dinv, esrc, N, E, NB2);

    // dense matmul xw1h = fp16(dinv * (x @ W1))
    xw1_kernel<<<(N + 63) / 64, tb, 0, stream>>>(x, W1, dinv, xw1h, N);

    // layer 1: chunk-phased gather-reduce -> hsh
    gather1<<<(N + 63) / 64, tb, 0, stream>>>(esrc, segc, dinv, xw1h, b1, hsh, N);

    // layer 2: chunk-phased gather-reduce -> agg2
    gather2<<<(N + 63) / 64, tb, 0, stream>>>(esrc, segc, dinv, hsh, agg2, N);

    // fused projection + log_softmax -> out
    final_kernel<<<nbN, tb, 0, stream>>>(agg2, W2, b2, out, N);
}

// Round 10
// 661.613 us; speedup vs baseline: 1.0693x; 1.0693x over previous
//
#include <hip/hip_runtime.h>
#include <hip/hip_bf16.h>
#include <hip/hip_fp16.h>

#define NDIM 100
#define HDIM 16
#define CDIM 20

#define BSH2   10                 // 1024 nodes per bucket
#define BMASK2 ((1 << BSH2) - 1)
#define NB2MAX 768                // supports N <= 786432
#define CH2    16384              // edges per scatter_sort block
#define CHSH   17                 // src chunk = src >> 17 (128K nodes = 4MB fp16 table)
#define LBUF_CAP 18432            // binC LDS staging capacity

// fp16 pack/unpack helpers (tables stored fp16, accumulation fp32)
__device__ inline float2 h2f2(unsigned u) {
    __half2 h = *reinterpret_cast<__half2*>(&u);
    return __half22float2(h);
}
__device__ inline unsigned f2h2(float a, float b) {
    __half2 h = __floats2half2_rn(a, b);
    return *reinterpret_cast<unsigned*>(&h);
}

// ---------------- pass A: bucket histogram -> bcnt[b] ----------------

__global__ __launch_bounds__(256) void histA(const int* __restrict__ dst,
                                             int* __restrict__ bcnt,
                                             int E, int NB2) {
    __shared__ int lh[NB2MAX];
    for (int t = threadIdx.x; t < NB2MAX; t += 256) lh[t] = 0;
    __syncthreads();

    int base = blockIdx.x * 8192;
    int endv = min(base + 8192, E);
    for (int e = base + threadIdx.x; e < endv; e += 256)
        atomicAdd(&lh[dst[e] >> BSH2], 1);
    __syncthreads();

    for (int t = threadIdx.x; t < NB2; t += 256) {
        int v = lh[t];
        if (v) atomicAdd(&bcnt[t], v);
    }
}

// ---- exclusive scan of bcnt in place (nb <= 2048), 1 block; also seeds gcur ----

__global__ __launch_bounds__(256) void scan_k2(int* __restrict__ bsum,
                                               int* __restrict__ gcur, int nb) {
    __shared__ int part[256];
    int t = threadIdx.x;
    int base = t * 8;
    int loc[8];
    int s = 0;
#pragma unroll
    for (int k = 0; k < 8; ++k) {
        int idx = base + k;
        loc[k] = (idx < nb) ? bsum[idx] : 0;
        s += loc[k];
    }
    part[t] = s;
    __syncthreads();
    for (int off = 1; off < 256; off <<= 1) {
        int add = (t >= off) ? part[t - off] : 0;
        __syncthreads();
        part[t] += add;
        __syncthreads();
    }
    int run = (t > 0) ? part[t - 1] : 0;
#pragma unroll
    for (int k = 0; k < 8; ++k) {
        int idx = base + k;
        if (idx < nb) { bsum[idx] = run; gcur[idx] = run; }
        run += loc[k];
    }
}

// ---------------- pass B: block-local counting sort in LDS + full-line copy-out ----

__global__ __launch_bounds__(1024) void scatter_sort(const int* __restrict__ src,
                                                     const int* __restrict__ dst,
                                                     int* __restrict__ gcur,
                                                     unsigned* __restrict__ tmp,
                                                     int E, int NB2) {
    __shared__ unsigned lbuf[CH2];   // 64 KB
    __shared__ int lcnt[1024];       // counts -> cursors
    __shared__ int lst[1024];        // local exclusive starts
    __shared__ int gb[1024];         // global run bases
    const int t = threadIdx.x;

    lcnt[t] = 0;
    __syncthreads();

    int base = blockIdx.x * CH2;
    int endv = min(base + CH2, E);
    for (int e = base + t; e < endv; e += 1024)
        atomicAdd(&lcnt[dst[e] >> BSH2], 1);
    __syncthreads();

    int c = lcnt[t];
    lst[t] = c;
    __syncthreads();
    for (int off = 1; off < 1024; off <<= 1) {
        int add = (t >= off) ? lst[t - off] : 0;
        __syncthreads();
        lst[t] += add;
        __syncthreads();
    }
    int ex = lst[t] - c;   // exclusive prefix

    int gbase = 0;
    if (t < NB2 && c > 0) gbase = atomicAdd(&gcur[t], c);
    gb[t]   = gbase;
    lst[t]  = ex;
    lcnt[t] = ex;
    __syncthreads();

    for (int e = base + t; e < endv; e += 1024) {
        int d = dst[e];
        int b = d >> BSH2;
        int pos = atomicAdd(&lcnt[b], 1);
        lbuf[pos] = ((unsigned)src[e] << BSH2) | (unsigned)(d & BMASK2);
    }
    __syncthreads();

    int grp = t >> 4, lane = t & 15;
    for (int b = grp; b < NB2; b += 64) {
        int s0 = lst[b], g0 = gb[b];
        int len = lcnt[b] - s0;
        for (int k = lane; k < len; k += 16)
            tmp[(size_t)g0 + k] = lbuf[s0 + k];
    }
}

// ---------------- pass C: (node, src-chunk) counting sort, LDS-staged copy-out ----------------
// One block per bucket. 4096 (node,chunk) bins; scatter into lbuf (LDS), then
// linear full-line copy-out to esrc. Emits segc=(end,deg,chunk-lens) + dinv.

__global__ __launch_bounds__(1024) void binC(const unsigned* __restrict__ tmp,
                                             const int* __restrict__ B0,
                                             int4* __restrict__ segc,
                                             float* __restrict__ dinv,
                                             int* __restrict__ esrc,
                                             int N, int E, int NB2) {
    __shared__ int lbuf[LBUF_CAP];   // 72 KB
    __shared__ int lh[4096];         // 16 KB: (node,chunk) counts -> local cursors
    __shared__ int part[1024];       // 4 KB
    int b = blockIdx.x, t = threadIdx.x;

    for (int i = t; i < 4096; i += 1024) lh[i] = 0;
    __syncthreads();

    int lo = B0[b];
    int hi = (b + 1 < NB2) ? B0[b + 1] : E;

    for (int i = lo + t; i < hi; i += 1024) {
        unsigned v = tmp[i];
        unsigned ch = min(v >> (BSH2 + CHSH), 3u);
        atomicAdd(&lh[((v & BMASK2) << 2) | ch], 1);
    }
    __syncthreads();

    int c0 = lh[4 * t], c1 = lh[4 * t + 1], c2 = lh[4 * t + 2], c3 = lh[4 * t + 3];
    int cnt = c0 + c1 + c2 + c3;
    part[t] = cnt;
    __syncthreads();
    for (int off = 1; off < 1024; off <<= 1) {
        int add = (t >= off) ? part[t - off] : 0;
        __syncthreads();
        part[t] += add;
        __syncthreads();
    }
    int endl = part[t];        // inclusive, bucket-local
    int st   = endl - cnt;     // bucket-local segment start

    // bucket-local cursors per (node,chunk)
    lh[4 * t]     = st;
    lh[4 * t + 1] = st + c0;
    lh[4 * t + 2] = st + c0 + c1;
    lh[4 * t + 3] = st + c0 + c1 + c2;

    int node = (b << BSH2) + t;
    if (node < N) {
        segc[node] = make_int4(lo + endl, cnt, (c0 << 16) | c1, (c2 << 16) | c3);
        dinv[node] = rsqrtf((float)(cnt + 1));   // +1 = self-loop
    }
    __syncthreads();

    bool fits = (hi - lo) <= LBUF_CAP;
    if (fits) {
        for (int i = lo + t; i < hi; i += 1024) {
            unsigned v = tmp[i];
            unsigned srcv = v >> BSH2;
            unsigned ch = min(srcv >> CHSH, 3u);
            int pos = atomicAdd(&lh[((v & BMASK2) << 2) | ch], 1);
            lbuf[pos] = (int)srcv;
        }
        __syncthreads();
        for (int i = lo + t; i < hi; i += 1024)
            esrc[i] = lbuf[i - lo];
    } else {
        for (int i = lo + t; i < hi; i += 1024) {
            unsigned v = tmp[i];
            unsigned srcv = v >> BSH2;
            unsigned ch = min(srcv >> CHSH, 3u);
            int pos = atomicAdd(&lh[((v & BMASK2) << 2) | ch], 1);
            esrc[(size_t)lo + pos] = (int)srcv;
        }
    }
}

// ---------------- xw1h = fp16( dinv[n] * (x @ W1) )  ([N,100] @ [100,16]) ----------------

__global__ __launch_bounds__(256) void xw1_kernel(const float* __restrict__ x,
                                                  const float* __restrict__ W1,
                                                  const float* __restrict__ dinv,
                                                  __half* __restrict__ xw1h, int N) {
    __shared__ float Ws[NDIM * HDIM];  // [k][j]
    for (int t = threadIdx.x; t < NDIM * HDIM; t += 256) Ws[t] = W1[t];
    __syncthreads();

    const int ln = threadIdx.x >> 2;
    const int q  = threadIdx.x & 3;
    const int node = blockIdx.x * 64 + ln;
    if (node >= N) return;

    const float4* xr  = reinterpret_cast<const float4*>(x + (size_t)node * NDIM);
    const float4* Ws4 = reinterpret_cast<const float4*>(Ws);

    float4 acc = make_float4(0.f, 0.f, 0.f, 0.f);
#pragma unroll
    for (int kk = 0; kk < NDIM / 4; ++kk) {
        float4 xv = xr[kk];
        float xs[4] = {xv.x, xv.y, xv.z, xv.w};
#pragma unroll
        for (int c = 0; c < 4; ++c) {
            float4 w = Ws4[(kk * 4 + c) * 4 + q];
            acc.x += xs[c] * w.x;
            acc.y += xs[c] * w.y;
            acc.z += xs[c] * w.z;
            acc.w += xs[c] * w.w;
        }
    }
    float dn = dinv[node];
    uint2 o;
    o.x = f2h2(dn * acc.x, dn * acc.y);
    o.y = f2h2(dn * acc.z, dn * acc.w);
    reinterpret_cast<uint2*>(xw1h)[(size_t)node * 4 + q] = o;
}

// ---------------- layer-1 gather (4 src-chunk phases): hsh = fp16(...) ----------------

__global__ __launch_bounds__(256) void gather1(const int* __restrict__ esrc,
                                               const int4* __restrict__ segc,
                                               const float* __restrict__ dinv,
                                               const __half* __restrict__ xw1h,
                                               const float* __restrict__ b1,
                                               __half* __restrict__ hsh, int N) {
    int g  = threadIdx.x >> 2;
    int f4 = threadIdx.x & 3;
    int n  = blockIdx.x * 64 + g;
    bool active = (n < N);

    const uint2* T = reinterpret_cast<const uint2*>(xw1h);
    int4 sc = make_int4(0, 0, 0, 0);
    float dn = 0.f;
    float4 a0 = make_float4(0.f, 0.f, 0.f, 0.f);
    float4 a1 = make_float4(0.f, 0.f, 0.f, 0.f);
    if (active) {
        sc = segc[n];
        dn = dinv[n];
        uint2 sv = T[(size_t)n * 4 + f4];
        float2 s01 = h2f2(sv.x), s23 = h2f2(sv.y);
        a0 = make_float4(s01.x, s01.y, s23.x, s23.y);  // self term
    }
    int lens[4] = {sc.z >> 16, sc.z & 0xffff, sc.w >> 16, sc.w & 0xffff};
    int j = sc.x - sc.y;  // start

    for (int c = 0; c < 4; ++c) {
        int e2 = j + lens[c];
        for (; j + 3 < e2; j += 4) {
            int i0 = esrc[j + 0], i1 = esrc[j + 1];
            int i2 = esrc[j + 2], i3 = esrc[j + 3];
            uint2 v0 = T[(size_t)i0 * 4 + f4];
            uint2 v1 = T[(size_t)i1 * 4 + f4];
            uint2 v2 = T[(size_t)i2 * 4 + f4];
            uint2 v3 = T[(size_t)i3 * 4 + f4];
            float2 p, q;
            p = h2f2(v0.x); q = h2f2(v0.y);
            a0.x += p.x; a0.y += p.y; a0.z += q.x; a0.w += q.y;
            p = h2f2(v1.x); q = h2f2(v1.y);
            a1.x += p.x; a1.y += p.y; a1.z += q.x; a1.w += q.y;
            p = h2f2(v2.x); q = h2f2(v2.y);
            a0.x += p.x; a0.y += p.y; a0.z += q.x; a0.w += q.y;
            p = h2f2(v3.x); q = h2f2(v3.y);
            a1.x += p.x; a1.y += p.y; a1.z += q.x; a1.w += q.y;
        }
        for (; j < e2; ++j) {
            int s = esrc[j];
            uint2 v = T[(size_t)s * 4 + f4];
            float2 p = h2f2(v.x), q = h2f2(v.y);
            a0.x += p.x; a0.y += p.y; a0.z += q.x; a0.w += q.y;
        }
        if (c < 3) __syncthreads();
    }
    if (active) {
        float4 acc = make_float4(a0.x + a1.x, a0.y + a1.y, a0.z + a1.z, a0.w + a1.w);
        float4 bv = reinterpret_cast<const float4*>(b1)[f4];
        float hx = dn * fmaxf(dn * acc.x + bv.x, 0.f);
        float hy = dn * fmaxf(dn * acc.y + bv.y, 0.f);
        float hz = dn * fmaxf(dn * acc.z + bv.z, 0.f);
        float hw = dn * fmaxf(dn * acc.w + bv.w, 0.f);
        uint2 o;
        o.x = f2h2(hx, hy);
        o.y = f2h2(hz, hw);
        reinterpret_cast<uint2*>(hsh)[(size_t)n * 4 + f4] = o;
    }
}

// ---------------- layer-2 gather (4 src-chunk phases): agg2 fp32 ----------------

__global__ __launch_bounds__(256) void gather2(const int* __restrict__ esrc,
                                               const int4* __restrict__ segc,
                                               const float* __restrict__ dinv,
                                               const __half* __restrict__ hsh,
                                               float* __restrict__ agg2, int N) {
    int g  = threadIdx.x >> 2;
    int f4 = threadIdx.x & 3;
    int n  = blockIdx.x * 64 + g;
    bool active = (n < N);

    const uint2* T = reinterpret_cast<const uint2*>(hsh);
    int4 sc = make_int4(0, 0, 0, 0);
    float dn = 0.f;
    float4 a0 = make_float4(0.f, 0.f, 0.f, 0.f);
    float4 a1 = make_float4(0.f, 0.f, 0.f, 0.f);
    if (active) {
        sc = segc[n];
        dn = dinv[n];
        uint2 sv = T[(size_t)n * 4 + f4];
        float2 s01 = h2f2(sv.x), s23 = h2f2(sv.y);
        a0 = make_float4(s01.x, s01.y, s23.x, s23.y);  // self term
    }
    int lens[4] = {sc.z >> 16, sc.z & 0xffff, sc.w >> 16, sc.w & 0xffff};
    int j = sc.x - sc.y;  // start

    for (int c = 0; c < 4; ++c) {
        int e2 = j + lens[c];
        for (; j + 3 < e2; j += 4) {
            int i0 = esrc[j + 0], i1 = esrc[j + 1];
            int i2 = esrc[j + 2], i3 = esrc[j + 3];
            uint2 v0 = T[(size_t)i0 * 4 + f4];
            uint2 v1 = T[(size_t)i1 * 4 + f4];
            uint2 v2 = T[(size_t)i2 * 4 + f4];
            uint2 v3 = T[(size_t)i3 * 4 + f4];
            float2 p, q;
            p = h2f2(v0.x); q = h2f2(v0.y);
            a0.x += p.x; a0.y += p.y; a0.z += q.x; a0.w += q.y;
            p = h2f2(v1.x); q = h2f2(v1.y);
            a1.x += p.x; a1.y += p.y; a1.z += q.x; a1.w += q.y;
            p = h2f2(v2.x); q = h2f2(v2.y);
            a0.x += p.x; a0.y += p.y; a0.z += q.x; a0.w += q.y;
            p = h2f2(v3.x); q = h2f2(v3.y);
            a1.x += p.x; a1.y += p.y; a1.z += q.x; a1.w += q.y;
        }
        for (; j < e2; ++j) {
            int s = esrc[j];
            uint2 v = T[(size_t)s * 4 + f4];
            float2 p = h2f2(v.x), q = h2f2(v.y);
            a0.x += p.x; a0.y += p.y; a0.z += q.x; a0.w += q.y;
        }
        if (c < 3) __syncthreads();
    }
    if (active) {
        float4 o;
        o.x = dn * (a0.x + a1.x);
        o.y = dn * (a0.y + a1.y);
        o.z = dn * (a0.z + a1.z);
        o.w = dn * (a0.w + a1.w);
        reinterpret_cast<float4*>(agg2)[(size_t)n * 4 + f4] = o;
    }
}

// ---------------- final: out = log_softmax(agg2 @ W2 + b2) ----------------

__global__ __launch_bounds__(256) void final_kernel(const float* __restrict__ agg2,
                                                    const float* __restrict__ W2,
                                                    const float* __restrict__ b2,
                                                    float* __restrict__ out, int N) {
    __shared__ float W2t[CDIM * HDIM];  // [j][k]
    __shared__ float b2s[CDIM];
    for (int t = threadIdx.x; t < CDIM * HDIM; t += 256) {
        int j = t / HDIM, k = t % HDIM;
        W2t[t] = W2[k * CDIM + j];
    }
    for (int t = threadIdx.x; t < CDIM; t += 256) b2s[t] = b2[t];
    __syncthreads();

    int n = blockIdx.x * 256 + threadIdx.x;
    if (n >= N) return;

    float a[HDIM];
    const float4* a4 = reinterpret_cast<const float4*>(agg2 + (size_t)n * HDIM);
#pragma unroll
    for (int c = 0; c < HDIM / 4; ++c) {
        float4 v = a4[c];
        a[4 * c + 0] = v.x; a[4 * c + 1] = v.y;
        a[4 * c + 2] = v.z; a[4 * c + 3] = v.w;
    }
    float o[CDIM];
#pragma unroll
    for (int j = 0; j < CDIM; ++j) {
        const float4* w4 = reinterpret_cast<const float4*>(W2t + j * HDIM);
        float s = b2s[j];
#pragma unroll
        for (int c = 0; c < HDIM / 4; ++c) {
            float4 w = w4[c];
            s += a[4 * c + 0] * w.x + a[4 * c + 1] * w.y +
                 a[4 * c + 2] * w.z + a[4 * c + 3] * w.w;
        }
        o[j] = s;
    }
    float m = o[0];
#pragma unroll
    for (int j = 1; j < CDIM; ++j) m = fmaxf(m, o[j]);
    float s = 0.f;
#pragma unroll
    for (int j = 0; j < CDIM; ++j) s += __expf(o[j] - m);
    float l = __logf(s);
    float4* out4 = reinterpret_cast<float4*>(out + (size_t)n * CDIM);
#pragma unroll
    for (int c = 0; c < CDIM / 4; ++c)
        out4[c] = make_float4(o[4 * c + 0] - m - l, o[4 * c + 1] - m - l,
                              o[4 * c + 2] - m - l, o[4 * c + 3] - m - l);
}

// ---------------- launch ----------------

extern "C" void kernel_launch(void* const* d_in, const int* in_sizes, int n_in,
                              void* d_out, int out_size, void* d_ws, size_t ws_size,
                              hipStream_t stream) {
    const float* x  = (const float*)d_in[0];
    const int* edge = (const int*)d_in[1];   // [2, E] int32
    const float* W1 = (const float*)d_in[2];
    const float* b1 = (const float*)d_in[3];
    const float* W2 = (const float*)d_in[4];
    const float* b2 = (const float*)d_in[5];
    float* out = (float*)d_out;

    const int N = in_sizes[0] / NDIM;   // 500000
    const int E = in_sizes[1] / 2;      // 8000000
    const int* src = edge;
    const int* dst = edge + E;

    const int tb = 256;
    const int nbN = (N + tb - 1) / tb;
    const int NB2 = (N + BMASK2) >> BSH2;       // 489 coarse buckets

    char* ws = (char*)d_ws;
    size_t off = 0;
    int4*     segc   = (int4*)(ws + off);   off += (size_t)N * 16;
    float*    dinv   = (float*)(ws + off);  off += (size_t)N * 4;
    __half*   xw1h   = (__half*)(ws + off); off += (size_t)N * HDIM * 2;
    __half*   hsh    = (__half*)(ws + off); off += (size_t)N * HDIM * 2;
    float*    agg2   = (float*)(ws + off);  off += (size_t)N * HDIM * 4;
    int*      esrc   = (int*)(ws + off);    off += (size_t)E * 4;
    int*      bcnt   = (int*)(ws + off);    off += (size_t)NB2MAX * 4;
    int*      gcur   = (int*)(ws + off);    off += (size_t)NB2MAX * 4;

    // tmp (bucket-major packed edges, E*4 = 32MB) aliases agg2 (N*HDIM*4 = 32MB);
    // agg2 is only written by gather2, long after binC has consumed tmp.
    unsigned* tmp = (unsigned*)agg2;

    // ---- CSR build ----
    hipMemsetAsync(bcnt, 0, (size_t)NB2 * 4, stream);
    histA<<<(E + 8191) / 8192, tb, 0, stream>>>(dst, bcnt, E, NB2);
    scan_k2<<<1, tb, 0, stream>>>(bcnt, gcur, NB2);   // bcnt -> B0, seeds gcur
    scatter_sort<<<(E + CH2 - 1) / CH2, 1024, 0, stream>>>(src, dst, gcur, tmp, E, NB2);
    binC<<<NB2, 1024, 0, stream>>>(tmp, bcnt, segc, dinv, esrc, N, E, NB2);

    // dense matmul xw1h = fp16(dinv * (x @ W1))
    xw1_kernel<<<(N + 63) / 64, tb, 0, stream>>>(x, W1, dinv, xw1h, N);

    // layer 1: chunk-phased gather-reduce -> hsh
    gather1<<<(N + 63) / 64, tb, 0, stream>>>(esrc, segc, dinv, xw1h, b1, hsh, N);

    // layer 2: chunk-phased gather-reduce -> agg2
    gather2<<<(N + 63) / 64, tb, 0, stream>>>(esrc, segc, dinv, hsh, agg2, N);

    // fused projection + log_softmax -> out
    final_kernel<<<nbN, tb, 0, stream>>>(agg2, W2, b2, out, N);
}